// Round 3
// baseline (403.836 us; speedup 1.0000x reference)
//
#include <hip/hip_runtime.h>
#include <hip/hip_bf16.h>

// B=100000, C=64, R=128, H=32
// out[b,r,i,j] = sum_c w[b,r,c] * v[b,c,i]*v[b,c,j]
// w = relu(||v||_c @ W1 + b1) @ W2 + b2

#define NB 16      // batch elements per block
#define RT 8       // r rows per tile iteration (r = wid*2 + half)

typedef float f32x4 __attribute__((ext_vector_type(4)));
typedef __bf16 bf16x8 __attribute__((ext_vector_type(8)));

static __device__ __forceinline__ unsigned short bf_bits(float f) {
  __hip_bfloat16 h = __float2bfloat16(f);
  return *reinterpret_cast<const unsigned short*>(&h);
}
static __device__ __forceinline__ unsigned int pack_bf2(float a, float b) {
  return (unsigned int)bf_bits(a) | ((unsigned int)bf_bits(b) << 16);
}

// ---- kernel 0: W2 [32][8192] fp32 -> W2T [8192][32] bf16 in workspace ----
__global__ void prep_w2t(const float* __restrict__ W2, unsigned short* __restrict__ w2t) {
  int rc = blockIdx.x * 256 + threadIdx.x;   // 0..8191
  unsigned int u[16];
#pragma unroll
  for (int kp = 0; kp < 16; ++kp) {
    float a = W2[(size_t)(2 * kp) * 8192 + rc];
    float b = W2[(size_t)(2 * kp + 1) * 8192 + rc];
    u[kp] = pack_bf2(a, b);
  }
  unsigned int* dst = reinterpret_cast<unsigned int*>(w2t + (size_t)rc * 32);
#pragma unroll
  for (int j = 0; j < 16; ++j) dst[j] = u[j];
}

// ---- main fused kernel ----
// LDS layout (bytes):
//   [0, 18688)      W_lds bf16: [b:stride 584][r:stride 72][c]   (union: W1_lds f32[2048] during setup)
//   [18688, 23040)  s_lds f32:  [b:stride 68][c]
//   [23040, 24064)  h_lds bf16: [b:stride 32][k]
__global__ __launch_bounds__(256, 4)
void erl_main(const float* __restrict__ v, const float* __restrict__ W1,
              const float* __restrict__ b1, const float* __restrict__ b2,
              const unsigned short* __restrict__ w2t, float* __restrict__ out) {
  __shared__ __align__(16) char smem[24064];
  unsigned short* W_lds = reinterpret_cast<unsigned short*>(smem);
  float* W1_lds = reinterpret_cast<float*>(smem);
  float* s_lds = reinterpret_cast<float*>(smem + 18688);
  unsigned short* h_lds = reinterpret_cast<unsigned short*>(smem + 23040);

  const int t = threadIdx.x;
  const int b0 = blockIdx.x * NB;
  const int lane = t & 63;
  const int wid = t >> 6;
  const int x = lane >> 4;     // 0..3
  const int col = lane & 15;   // 0..15

  // ---------- setup: W1 -> LDS (coalesced), norms -> s_lds ----------
  {
    const f32x4* w1v = reinterpret_cast<const f32x4*>(W1);
    f32x4* w1d = reinterpret_cast<f32x4*>(W1_lds);
    w1d[t] = w1v[t];
    w1d[t + 256] = w1v[t + 256];
  }
#pragma unroll
  for (int j = 0; j < 4; ++j) {
    int p = t + j * 256;
    int b = p >> 6, c = p & 63;
    const float* vp = v + ((size_t)(b0 + b) * 64 + c) * 3;
    float vx = vp[0], vy = vp[1], vz = vp[2];
    s_lds[b * 68 + c] = sqrtf(vx * vx + vy * vy + vz * vz);
  }

  // ---------- setup: register-resident M fragments ----------
  // lane (wid,x,col) holds B-frag values M[b=wid*4+i][c=ch*32+x*8+e][s] with s=min(col,8)
  const int seff = (col < 9) ? col : 8;
  const int ei = seff / 3;          // lane-constant
  const int ej = seff - ei * 3;
  bf16x8 mfr[4][2];
#pragma unroll
  for (int i = 0; i < 4; ++i) {
    int b = wid * 4 + i;
#pragma unroll
    for (int ch = 0; ch < 2; ++ch) {
      const float* vb = v + ((size_t)(b0 + b) * 64 + ch * 32 + x * 8) * 3;  // 96B-aligned
      union { f32x4 q[6]; float f[24]; } u;
#pragma unroll
      for (int l = 0; l < 6; ++l) u.q[l] = reinterpret_cast<const f32x4*>(vb)[l];
      bf16x8 fr;
#pragma unroll
      for (int e = 0; e < 8; ++e) {
        float vx = u.f[e * 3 + 0], vy = u.f[e * 3 + 1], vz = u.f[e * 3 + 2];
        float pa = (ei == 0) ? vx : ((ei == 1) ? vy : vz);
        float pb = (ej == 0) ? vx : ((ej == 1) ? vy : vz);
        fr[e] = (__bf16)(pa * pb);
      }
      mfr[i][ch] = fr;
    }
  }
  __syncthreads();

  // ---------- tiny MLP: h[b][k], thread handles (b = t>>4, k = t&15 and +16) ----------
  {
    int b = t >> 4, kk = t & 15;
    float a0 = b1[kk], a1 = b1[kk + 16];
    const f32x4* srow = reinterpret_cast<const f32x4*>(s_lds + b * 68);
#pragma unroll
    for (int c4 = 0; c4 < 16; ++c4) {
      f32x4 sv = srow[c4];
#pragma unroll
      for (int uu = 0; uu < 4; ++uu) {
        int c = c4 * 4 + uu;
        a0 = fmaf(sv[uu], W1_lds[c * 32 + kk], a0);
        a1 = fmaf(sv[uu], W1_lds[c * 32 + kk + 16], a1);
      }
    }
    h_lds[b * 32 + kk] = bf_bits(fmaxf(a0, 0.f));
    h_lds[b * 32 + kk + 16] = bf_bits(fmaxf(a1, 0.f));
  }
  __syncthreads();

  // B-frag for stage1: h^T [K=32][N=16b]: lane holds h[b=col][k=x*8+e]
  bf16x8 hfrag = *reinterpret_cast<const bf16x8*>(&h_lds[col * 32 + x * 8]);

  // ---------- per-lane bases (all in-loop offsets are compile-time immediates) ----------
  const unsigned short* ap0 = w2t + (size_t)wid * 4096 + col * 32 + x * 8;  // tiles wid*8+0..3 (+i*512)
  const unsigned short* ap1 = ap0 + 2048;                                    // tiles wid*8+4..7
  const float* b2p = b2 + wid * 128 + x * 4;                                 // +half*64 + i*16
  const int w_widx = col * 584 + wid * 144 + x * 4;        // W_lds write base (elems); + half*72 + i*16
  const int w_ridx = wid * 4 * 584 + (col & 7) * 72 + x * 8;  // W_lds read base; + i*584 + ch*32
  float* op[4];
#pragma unroll
  for (int i = 0; i < 4; ++i)
    op[i] = out + (size_t)(b0 + wid * 4 + i) * 1152 + x * 36 + col;
  const bool do_store = (x < 2) && (col < 9);

  for (int rt = 0; rt < 128 / RT; ++rt) {
    // ---------- stage 1: w[rc][b] = W2T[rc][k] @ h^T[k][b] + b2[rc] ----------
#pragma unroll
    for (int half = 0; half < 2; ++half) {
      const unsigned short* ap = half ? ap1 : ap0;
      bf16x8 af[4];
      f32x4 acc1[4];
#pragma unroll
      for (int i = 0; i < 4; ++i) {
        af[i] = *reinterpret_cast<const bf16x8*>(ap + i * 512);
        acc1[i] = *reinterpret_cast<const f32x4*>(b2p + half * 64 + i * 16);
      }
#pragma unroll
      for (int i = 0; i < 4; ++i) {
        acc1[i] = __builtin_amdgcn_mfma_f32_16x16x32_bf16(af[i], hfrag, acc1[i], 0, 0, 0);
        // D: lane holds w[rc = tile*16 + x*4 + q][b=col]; r = wid*2+half (compile-known), c = i*16+x*4+q
        unsigned int* wp = reinterpret_cast<unsigned int*>(&W_lds[w_widx + half * 72 + i * 16]);
        wp[0] = pack_bf2(acc1[i][0], acc1[i][1]);
        wp[1] = pack_bf2(acc1[i][2], acc1[i][3]);
      }
    }
    ap0 += 16384; ap1 += 16384; b2p += 512;
    __syncthreads();

    // ---------- stage 2: O[b][r][e] = W[r][c] @ M[c][e], direct global store ----------
#pragma unroll
    for (int i = 0; i < 4; ++i) {
      f32x4 acc2 = {0.f, 0.f, 0.f, 0.f};
#pragma unroll
      for (int ch = 0; ch < 2; ++ch) {
        bf16x8 a2 = *reinterpret_cast<const bf16x8*>(&W_lds[w_ridx + i * 584 + ch * 32]);
        acc2 = __builtin_amdgcn_mfma_f32_16x16x32_bf16(a2, mfr[i][ch], acc2, 0, 0, 0);
      }
      if (do_store) {
        float* p = op[i];
#pragma unroll
        for (int q = 0; q < 4; ++q) p[q * 9] = acc2[q];   // r = x*4+q, e = col
      }
      op[i] += 72;
    }
    __syncthreads();
  }
}

extern "C" void kernel_launch(void* const* d_in, const int* in_sizes, int n_in,
                              void* d_out, int out_size, void* d_ws, size_t ws_size,
                              hipStream_t stream) {
  const float* v  = (const float*)d_in[0];   // [100000,64,3]
  const float* W1 = (const float*)d_in[1];   // [64,32]
  const float* b1 = (const float*)d_in[2];   // [32]
  const float* W2 = (const float*)d_in[3];   // [32,8192]
  const float* b2 = (const float*)d_in[4];   // [8192]
  float* out = (float*)d_out;                // [100000,128,3,3]

  unsigned short* w2t = (unsigned short*)d_ws;  // [8192][32] bf16 = 512 KB

  prep_w2t<<<32, 256, 0, stream>>>(W2, w2t);
  erl_main<<<100000 / NB, 256, 0, stream>>>(v, W1, b1, b2, w2t, out);
}

// Round 4
// 401.542 us; speedup vs baseline: 1.0057x; 1.0057x over previous
//
#include <hip/hip_runtime.h>
#include <hip/hip_bf16.h>

// B=100000, C=64, R=128, H=32
// out[b,r,i,j] = sum_c w[b,r,c] * v[b,c,i]*v[b,c,j]
// w = relu(||v||_c @ W1 + b1) @ W2 + b2

#define NB 16      // batch elements per block
#define RT 16      // r rows per iteration; 8 iterations total

typedef float f32x4 __attribute__((ext_vector_type(4)));
typedef __bf16 bf16x8 __attribute__((ext_vector_type(8)));

static __device__ __forceinline__ unsigned short bf_bits(float f) {
  __hip_bfloat16 h = __float2bfloat16(f);
  return *reinterpret_cast<const unsigned short*>(&h);
}
static __device__ __forceinline__ unsigned int pack_bf2(float a, float b) {
  return (unsigned int)bf_bits(a) | ((unsigned int)bf_bits(b) << 16);
}

// ---- kernel 0: W2 [32][8192] fp32 -> W2T [8192][32] bf16 in workspace ----
__global__ void prep_w2t(const float* __restrict__ W2, unsigned short* __restrict__ w2t) {
  int rc = blockIdx.x * 256 + threadIdx.x;   // 0..8191
  unsigned int u[16];
#pragma unroll
  for (int kp = 0; kp < 16; ++kp) {
    float a = W2[(size_t)(2 * kp) * 8192 + rc];
    float b = W2[(size_t)(2 * kp + 1) * 8192 + rc];
    u[kp] = pack_bf2(a, b);
  }
  unsigned int* dst = reinterpret_cast<unsigned int*>(w2t + (size_t)rc * 32);
#pragma unroll
  for (int j = 0; j < 16; ++j) dst[j] = u[j];
}

// ---- main fused kernel ----
// LDS: W_lds bf16 [b:stride 1168][r:stride 72][c], 16 b x 16 r -> 37376 B.
// Setup-phase union inside the same region:
//   [0,8192)      W1_lds f32[2048]
//   [8192,12544)  s_lds f32 [b:stride 68][c]
//   [12544,13568) h_lds bf16 [b:stride 32][k]
// Bank math (32 banks x 4B):
//  stage-1 b64 write, dword idx = 584*col + 36*r + 8*tt + 2*x (+q/2):
//    fixed instr: bank = (8*col + 2*x) % 32 -> 128 dwords spread 4/bank uniform.
//  stage-2 b128 read, dword idx = col*36 + x*4 + const:
//    bank = 4*((col+x)%8) -> 8 lane-groups x 4-bank spans, 8 dwords/bank uniform.
__global__ __launch_bounds__(256, 4)
void erl_main(const float* __restrict__ v, const float* __restrict__ W1,
              const float* __restrict__ b1, const float* __restrict__ b2,
              const unsigned short* __restrict__ w2t, float* __restrict__ out) {
  __shared__ __align__(16) char smem[37376];
  unsigned short* W_lds = reinterpret_cast<unsigned short*>(smem);
  float* W1_lds = reinterpret_cast<float*>(smem);
  float* s_lds = reinterpret_cast<float*>(smem + 8192);
  unsigned short* h_lds = reinterpret_cast<unsigned short*>(smem + 12544);

  const int t = threadIdx.x;
  const int b0 = blockIdx.x * NB;
  const int lane = t & 63;
  const int wid = t >> 6;
  const int x = lane >> 4;     // 0..3
  const int col = lane & 15;   // 0..15

  // ---------- setup: W1 -> LDS, norms -> s_lds ----------
  {
    const f32x4* w1v = reinterpret_cast<const f32x4*>(W1);
    f32x4* w1d = reinterpret_cast<f32x4*>(W1_lds);
    w1d[t] = w1v[t];
    w1d[t + 256] = w1v[t + 256];
  }
#pragma unroll
  for (int j = 0; j < 4; ++j) {
    int p = t + j * 256;
    int b = p >> 6, c = p & 63;
    const float* vp = v + ((size_t)(b0 + b) * 64 + c) * 3;
    float vx = vp[0], vy = vp[1], vz = vp[2];
    s_lds[b * 68 + c] = sqrtf(vx * vx + vy * vy + vz * vz);
  }

  // ---------- setup: register-resident M fragments ----------
  // lane holds B-frag M[b=wid*4+i][c=ch*32+x*8+e][s=min(col,8)]
  const int seff = (col < 9) ? col : 8;
  const int ei = seff / 3;
  const int ej = seff - ei * 3;
  bf16x8 mfr[4][2];
#pragma unroll
  for (int i = 0; i < 4; ++i) {
    int b = wid * 4 + i;
#pragma unroll
    for (int ch = 0; ch < 2; ++ch) {
      const float* vb = v + ((size_t)(b0 + b) * 64 + ch * 32 + x * 8) * 3;
      union { f32x4 q[6]; float f[24]; } u;
#pragma unroll
      for (int l = 0; l < 6; ++l) u.q[l] = reinterpret_cast<const f32x4*>(vb)[l];
      bf16x8 fr;
#pragma unroll
      for (int e = 0; e < 8; ++e) {
        float vx = u.f[e * 3 + 0], vy = u.f[e * 3 + 1], vz = u.f[e * 3 + 2];
        float pa = (ei == 0) ? vx : ((ei == 1) ? vy : vz);
        float pb = (ej == 0) ? vx : ((ej == 1) ? vy : vz);
        fr[e] = (__bf16)(pa * pb);
      }
      mfr[i][ch] = fr;
    }
  }
  __syncthreads();

  // ---------- tiny MLP: h[b][k] ----------
  {
    int b = t >> 4, kk = t & 15;
    float a0 = b1[kk], a1 = b1[kk + 16];
    const f32x4* srow = reinterpret_cast<const f32x4*>(s_lds + b * 68);
#pragma unroll
    for (int c4 = 0; c4 < 16; ++c4) {
      f32x4 sv = srow[c4];
#pragma unroll
      for (int uu = 0; uu < 4; ++uu) {
        int c = c4 * 4 + uu;
        a0 = fmaf(sv[uu], W1_lds[c * 32 + kk], a0);
        a1 = fmaf(sv[uu], W1_lds[c * 32 + kk + 16], a1);
      }
    }
    h_lds[b * 32 + kk] = bf_bits(fmaxf(a0, 0.f));
    h_lds[b * 32 + kk + 16] = bf_bits(fmaxf(a1, 0.f));
  }
  __syncthreads();

  // B-frag for stage1: lane holds h[b=col][k=x*8+e]
  bf16x8 hfrag = *reinterpret_cast<const bf16x8*>(&h_lds[col * 32 + x * 8]);
  __syncthreads();   // protect h region before W_lds overwrites it

  // ---------- per-lane bases ----------
  // stage-1: wave wid owns tiles tt=0..15 (rc tile = wid*16+tt), rcg = rt*1024 + (wid*16+tt)*16
  const unsigned short* ap = w2t + (size_t)wid * 8192 + col * 32 + x * 8;  // + tt*512; += 32768/rt
  const float* b2p = b2 + wid * 256 + x * 4;                               // + tt*16;  += 1024/rt
  const int w_widx = col * 1168 + wid * 288 + x * 4;     // + ck*72 + jj*16
  const int w_ridx = wid * 4672 + col * 72 + x * 8;      // + i*1168 + ch*32
  float* op[4];
#pragma unroll
  for (int i = 0; i < 4; ++i)
    op[i] = out + (size_t)(b0 + wid * 4 + i) * 1152 + x * 36 + col;   // + rt*144; p[q*9]
  const bool do_store = (col < 9);

  // ---------- software pipeline: preload chunk 0 of rt=0 ----------
  bf16x8 afA[4], afB[4];
  f32x4 bsA[4];
#pragma unroll
  for (int jj = 0; jj < 4; ++jj) {
    afA[jj] = *reinterpret_cast<const bf16x8*>(ap + jj * 512);
    bsA[jj] = *reinterpret_cast<const f32x4*>(b2p + jj * 16);
  }

  for (int rt = 0; rt < 8; ++rt) {
    // ---------- stage 1: w[rc][b] = W2T @ h^T + b2, chunk-pipelined ----------
#pragma unroll
    for (int ck = 0; ck < 4; ++ck) {
      if (ck < 3) {
#pragma unroll
        for (int jj = 0; jj < 4; ++jj) {
          int tt = (ck + 1) * 4 + jj;
          afB[jj] = *reinterpret_cast<const bf16x8*>(ap + tt * 512);
        }
      }
#pragma unroll
      for (int jj = 0; jj < 4; ++jj) {
        f32x4 acc = (ck == 0) ? bsA[jj]
                  : *reinterpret_cast<const f32x4*>(b2p + (ck * 4 + jj) * 16);
        acc = __builtin_amdgcn_mfma_f32_16x16x32_bf16(afA[jj], hfrag, acc, 0, 0, 0);
        // lane holds w[rc=(wid*16+ck*4+jj)*16 + x*4+q][b=col]; r=wid*4+ck, c=jj*16+x*4+q
        unsigned int* wp = reinterpret_cast<unsigned int*>(&W_lds[w_widx + ck * 72 + jj * 16]);
        wp[0] = pack_bf2(acc[0], acc[1]);
        wp[1] = pack_bf2(acc[2], acc[3]);
      }
      if (ck < 3) {
#pragma unroll
        for (int jj = 0; jj < 4; ++jj) afA[jj] = afB[jj];
      }
    }
    ap += 32768; b2p += 1024;
    __syncthreads();   // sync1: W_lds ready

    // ---------- prefetch chunk 0 of next rt (in flight during stage 2) ----------
    if (rt < 7) {
#pragma unroll
      for (int jj = 0; jj < 4; ++jj) {
        afA[jj] = *reinterpret_cast<const bf16x8*>(ap + jj * 512);
        bsA[jj] = *reinterpret_cast<const f32x4*>(b2p + jj * 16);
      }
    }

    // ---------- stage 2: O[b][r=col? no: r rows 16][e] = W @ M, direct store ----------
#pragma unroll
    for (int i = 0; i < 4; ++i) {
      bf16x8 a20 = *reinterpret_cast<const bf16x8*>(&W_lds[w_ridx + i * 1168]);
      bf16x8 a21 = *reinterpret_cast<const bf16x8*>(&W_lds[w_ridx + i * 1168 + 32]);
      f32x4 acc2 = {0.f, 0.f, 0.f, 0.f};
      acc2 = __builtin_amdgcn_mfma_f32_16x16x32_bf16(a20, mfr[i][0], acc2, 0, 0, 0);
      acc2 = __builtin_amdgcn_mfma_f32_16x16x32_bf16(a21, mfr[i][1], acc2, 0, 0, 0);
      if (do_store) {
        float* p = op[i];
        p[0] = acc2[0]; p[9] = acc2[1]; p[18] = acc2[2]; p[27] = acc2[3];  // r=x*4+q, e=col
      }
      op[i] += 144;
    }
    __syncthreads();   // sync2: WAR before next stage-1 ds_write (also lands prefetch)
  }
}

extern "C" void kernel_launch(void* const* d_in, const int* in_sizes, int n_in,
                              void* d_out, int out_size, void* d_ws, size_t ws_size,
                              hipStream_t stream) {
  const float* v  = (const float*)d_in[0];   // [100000,64,3]
  const float* W1 = (const float*)d_in[1];   // [64,32]
  const float* b1 = (const float*)d_in[2];   // [32]
  const float* W2 = (const float*)d_in[3];   // [32,8192]
  const float* b2 = (const float*)d_in[4];   // [8192]
  float* out = (float*)d_out;                // [100000,128,3,3]

  unsigned short* w2t = (unsigned short*)d_ws;  // [8192][32] bf16 = 512 KB

  prep_w2t<<<32, 256, 0, stream>>>(W2, w2t);
  erl_main<<<100000 / NB, 256, 0, stream>>>(v, W1, b1, b2, w2t, out);
}